// Round 3
// baseline (130.464 us; speedup 1.0000x reference)
//
#include <hip/hip_runtime.h>
#include <stdint.h>

typedef __attribute__((ext_vector_type(8))) __bf16 bf16x8;
typedef __attribute__((ext_vector_type(4))) float f32x4;

__device__ __forceinline__ unsigned short f2bf(float f) {
  union { float f; unsigned int u; } v; v.f = f;
  unsigned int u = v.u;
  u = (u + 0x7FFFu + ((u >> 16) & 1u)) >> 16;   // RNE
  return (unsigned short)u;
}
__device__ __forceinline__ float bf2f(unsigned int u) {
  union { unsigned int u; float f; } v; v.u = u << 16;
  return v.f;
}

// ---------------------------------------------------------------------------
// Kernel 1: transpose + bf16-convert the three DxD weight matrices:
// Wt[n][k] = (bf16) W[k][n]  (B-operand fragments read 16B contiguous in K).
// ---------------------------------------------------------------------------
__global__ __launch_bounds__(256) void wconv(
    const float* __restrict__ Wa, const float* __restrict__ Wsh,
    const float* __restrict__ Wsc,
    unsigned short* __restrict__ Oa, unsigned short* __restrict__ Osh,
    unsigned short* __restrict__ Osc)
{
  const float* W; unsigned short* O;
  if (blockIdx.z == 0)      { W = Wa;  O = Oa; }
  else if (blockIdx.z == 1) { W = Wsh; O = Osh; }
  else                      { W = Wsc; O = Osc; }
  const int k0 = blockIdx.x * 64;
  const int n0 = blockIdx.y * 64;
  __shared__ float t[64][65];
  const int r = threadIdx.x >> 4;
  const int c4 = threadIdx.x & 15;
#pragma unroll
  for (int i = 0; i < 4; ++i) {
    const int row = r + i * 16;
    const float4 v = *(const float4*)(W + (size_t)(k0 + row) * 1024 + n0 + c4 * 4);
    t[row][c4 * 4 + 0] = v.x; t[row][c4 * 4 + 1] = v.y;
    t[row][c4 * 4 + 2] = v.z; t[row][c4 * 4 + 3] = v.w;
  }
  __syncthreads();
#pragma unroll
  for (int i = 0; i < 4; ++i) {
    const int nr = r + i * 16;
    ushort4 o;
    o.x = f2bf(t[c4 * 4 + 0][nr]);
    o.y = f2bf(t[c4 * 4 + 1][nr]);
    o.z = f2bf(t[c4 * 4 + 2][nr]);
    o.w = f2bf(t[c4 * 4 + 3][nr]);
    *(ushort4*)(O + (size_t)(n0 + nr) * 1024 + k0 + c4 * 4) = o;
  }
}

// ---------------------------------------------------------------------------
// Kernel 2: triple GEMM with SHARED A (associativity: the Gaussian row-mix
// commutes with the channel matmuls, so all three GEMMs consume x directly):
//   ya  = relu(x@Wa + ba)      -> bf16 to ws
//   ysh = x@Wsh, ysc = x@Wsc   -> packed (bf16,bf16) u32 into d_out slots
// BM=128 BN=128 BK=64, 512 thr (8 waves 2Mx4N), double-buffered LDS (128 KB),
// 2-phase: issue next tile's loads BEFORE the MFMA phase (T3-minimum recipe).
// ---------------------------------------------------------------------------
__global__ __launch_bounds__(512, 2) void fused_gemm(
    const float* __restrict__ x,
    const unsigned short* __restrict__ Wta, const unsigned short* __restrict__ Wts,
    const unsigned short* __restrict__ Wtc,
    const float* __restrict__ ba,
    unsigned short* __restrict__ ya, unsigned int* __restrict__ pk)
{
  __shared__ unsigned short sX[2][128 * 64];
  __shared__ unsigned short sA[2][128 * 64];
  __shared__ unsigned short sS[2][128 * 64];
  __shared__ unsigned short sC[2][128 * 64];

  const int tid = threadIdx.x;
  const int lane = tid & 63;
  const int wid = tid >> 6;
  const int wm = wid >> 2;
  const int wn = wid & 3;

  const int bid = blockIdx.x;        // 512 blocks
  const int bn0 = (bid & 7) * 128;   // XCD-friendly: one N column per XCD
  const int bm0 = (bid >> 3) * 128;

  // staging map (global_load_lds): physical LDS 16B slot -> (row,col), with
  // the XOR swizzle pre-applied on the GLOBAL source (rule #21).
  int rowS[2], colS[2];
#pragma unroll
  for (int p = 0; p < 2; ++p) {
    const int po = (p * 512 + tid) * 16;
    const int r = po >> 7;
    const int lo = po ^ ((r & 7) << 4);
    rowS[p] = r;
    colS[p] = (lo & 127) >> 1;
  }

  // X reg-staging map (f32 -> bf16 -> swizzled ds_write)
  const int xr0 = tid >> 4;          // 0..31
  const int xc  = (tid & 15) * 4;    // f32 col
  const int xsw = (xr0 & 7) << 4;

  const int lr = lane & 15;
  const int lk = lane >> 4;

  f32x4 accA[4][2], accS[4][2], accC[4][2];
  const f32x4 z = {0.f, 0.f, 0.f, 0.f};
#pragma unroll
  for (int m = 0; m < 4; ++m)
#pragma unroll
    for (int j = 0; j < 2; ++j) { accA[m][j] = z; accS[m][j] = z; accC[m][j] = z; }

  auto stageB = [&](int k0, int buf) {
#pragma unroll
    for (int p = 0; p < 2; ++p) {
      const size_t roff = (size_t)(bn0 + rowS[p]) * 1024 + k0 + colS[p];
      const int doff = (p * 512 + (wid << 6)) * 8;   // in us elements
      __builtin_amdgcn_global_load_lds(
          (const __attribute__((address_space(1))) void*)(Wta + roff),
          (__attribute__((address_space(3))) void*)(&sA[buf][0] + doff), 16, 0, 0);
      __builtin_amdgcn_global_load_lds(
          (const __attribute__((address_space(1))) void*)(Wts + roff),
          (__attribute__((address_space(3))) void*)(&sS[buf][0] + doff), 16, 0, 0);
      __builtin_amdgcn_global_load_lds(
          (const __attribute__((address_space(1))) void*)(Wtc + roff),
          (__attribute__((address_space(3))) void*)(&sC[buf][0] + doff), 16, 0, 0);
    }
  };
  auto writeX = [&](int buf, const float4* xv) {
#pragma unroll
    for (int i = 0; i < 4; ++i) {
      ushort4 o;
      o.x = f2bf(xv[i].x); o.y = f2bf(xv[i].y);
      o.z = f2bf(xv[i].z); o.w = f2bf(xv[i].w);
      const int row = i * 32 + xr0;
      const int po = (row * 128 + xc * 2) ^ xsw;
      *(ushort4*)((char*)&sX[buf][0] + po) = o;
    }
  };

  // prologue: stage tile 0 into buf 0
  float4 xv[4];
#pragma unroll
  for (int i = 0; i < 4; ++i)
    xv[i] = *(const float4*)(x + (size_t)(bm0 + i * 32 + xr0) * 1024 + 0 + xc);
  stageB(0, 0);
  writeX(0, xv);
  __syncthreads();   // drains vmcnt(0) + lgkmcnt(0)

  for (int kt = 0; kt < 16; ++kt) {
    const int cur = kt & 1, nxt = cur ^ 1;
    const bool pf = (kt + 1) < 16;
    if (pf) {
      const int k0n = (kt + 1) * 64;
#pragma unroll
      for (int i = 0; i < 4; ++i)
        xv[i] = *(const float4*)(x + (size_t)(bm0 + i * 32 + xr0) * 1024 + k0n + xc);
      stageB(k0n, nxt);
    }

#pragma unroll
    for (int s = 0; s < 2; ++s) {
      bf16x8 ax[4], bA[2], bS[2], bC[2];
#pragma unroll
      for (int m = 0; m < 4; ++m) {
        const int row = wm * 64 + m * 16 + lr;
        const int po = (row * 128 + (s * 32 + lk * 8) * 2) ^ ((row & 7) << 4);
        ax[m] = *(const bf16x8*)((const char*)&sX[cur][0] + po);
      }
#pragma unroll
      for (int j = 0; j < 2; ++j) {
        const int row = wn * 32 + j * 16 + lr;
        const int po = (row * 128 + (s * 32 + lk * 8) * 2) ^ ((row & 7) << 4);
        bA[j] = *(const bf16x8*)((const char*)&sA[cur][0] + po);
        bS[j] = *(const bf16x8*)((const char*)&sS[cur][0] + po);
        bC[j] = *(const bf16x8*)((const char*)&sC[cur][0] + po);
      }
      __builtin_amdgcn_s_setprio(1);
#pragma unroll
      for (int m = 0; m < 4; ++m)
#pragma unroll
        for (int j = 0; j < 2; ++j) {
          accA[m][j] = __builtin_amdgcn_mfma_f32_16x16x32_bf16(ax[m], bA[j], accA[m][j], 0, 0, 0);
          accS[m][j] = __builtin_amdgcn_mfma_f32_16x16x32_bf16(ax[m], bS[j], accS[m][j], 0, 0, 0);
          accC[m][j] = __builtin_amdgcn_mfma_f32_16x16x32_bf16(ax[m], bC[j], accC[m][j], 0, 0, 0);
        }
      __builtin_amdgcn_s_setprio(0);
    }

    if (pf) writeX(nxt, xv);   // compiler inserts the vmcnt wait for xv
    __syncthreads();           // drains vmcnt(0) (B tiles) + lgkm (X writes)
  }

  // epilogue. C/D layout: col=lane&15, row=(lane>>4)*4+reg [measured m89/m91]
#pragma unroll
  for (int j = 0; j < 2; ++j) {
    const int n = bn0 + wn * 32 + j * 16 + lr;
    const float Ba = ba[n];
#pragma unroll
    for (int m = 0; m < 4; ++m) {
      const int rbase = bm0 + wm * 64 + m * 16 + lk * 4;
#pragma unroll
      for (int r = 0; r < 4; ++r) {
        const size_t idx = (size_t)(rbase + r) * 1024 + n;
        const float aff = fmaxf(accA[m][j][r] + Ba, 0.0f);
        ya[idx] = f2bf(aff);
        pk[idx] = (unsigned int)f2bf(accS[m][j][r]) |
                  ((unsigned int)f2bf(accC[m][j][r]) << 16);
      }
    }
  }
}

// ---------------------------------------------------------------------------
// Kernel 3: causal Gaussian filter along t + combine, IN PLACE over d_out.
//   shift = filter(ysh)+bsh; scale = filter(ysc)+bsc; out = scale*ya + shift
// Each block owns one (batch, 32-col slice); 16 half-wave segments cover all
// 1024 t. Halo (15 rows) pre-read into regs before a barrier, so the f32
// overwrites never race the bf16 reads. Static 16-row window (rule #20).
// ---------------------------------------------------------------------------
__global__ __launch_bounds__(512) void filter_combine(
    void* slab,                         // d_out: read packed u32, write f32
    const unsigned short* __restrict__ ya,
    const float* __restrict__ bshift, const float* __restrict__ bscale)
{
  const unsigned int* pk = (const unsigned int*)slab;
  float* outf = (float*)slab;

  const int tid = threadIdx.x;
  const int b = blockIdx.x >> 5;            // 8 batches
  const int n0 = (blockIdx.x & 31) << 5;    // 32 col-slices
  const int lane = tid & 63;
  const int w = tid >> 6;                   // 0..7
  const int seg = (w << 1) | (lane >> 5);   // 0..15, 64 t-rows each
  const int col = lane & 31;
  const int n = n0 + col;
  const int t0 = seg * 64;
  const size_t base = (size_t)b * 1024 * 1024 + n;  // + t*1024

  float g[16];
#pragma unroll
  for (int k = 0; k < 16; ++k) g[k] = __expf(-(float)(k * k) * 0.125f);
  float nfull = 0.f;
#pragma unroll
  for (int k = 0; k < 16; ++k) nfull += g[k];
  const float invf = 1.0f / nfull;

  // halo pre-read: rows t0-15 .. t0-1 (zeros at batch start)
  float psh[15], psc[15];
#pragma unroll
  for (int i = 0; i < 15; ++i) {
    float vs = 0.f, vc = 0.f;
    if (t0 > 0) {
      const unsigned int u = pk[base + (size_t)(t0 - 15 + i) * 1024];
      vs = bf2f(u & 0xffffu); vc = bf2f(u >> 16);
    }
    psh[i] = vs; psc[i] = vc;
  }
  __syncthreads();   // all halo reads complete before any f32 overwrite

  const float bs = bshift[n];
  const float bc = bscale[n];

  for (int c = 0; c < 4; ++c) {             // 4 chunks of 16 t-rows
    const int T = t0 + c * 16;
    unsigned int cu[16];
#pragma unroll
    for (int u = 0; u < 16; ++u) cu[u] = pk[base + (size_t)(T + u) * 1024];
    unsigned short yv[16];
#pragma unroll
    for (int u = 0; u < 16; ++u) yv[u] = ya[base + (size_t)(T + u) * 1024];
    float csh[16], csc[16];
#pragma unroll
    for (int u = 0; u < 16; ++u) {
      csh[u] = bf2f(cu[u] & 0xffffu);
      csc[u] = bf2f(cu[u] >> 16);
    }
#pragma unroll
    for (int u = 0; u < 16; ++u) {
      float fs = 0.f, fc = 0.f;
#pragma unroll
      for (int k = 0; k < 16; ++k) {
        const int d = u - k;
        const float vs = (d >= 0) ? csh[d] : psh[15 + d];
        const float vc = (d >= 0) ? csc[d] : psc[15 + d];
        fs = fmaf(g[k], vs, fs);
        fc = fmaf(g[k], vc, fc);
      }
      const int t = T + u;
      float inv = invf;
      if (t < 15) {                          // batch start: partial norm
        float s = 0.f;
#pragma unroll
        for (int k = 0; k < 16; ++k) s += (k <= t) ? g[k] : 0.f;
        inv = 1.0f / s;
      }
      const float shiftv = fs * inv + bs;
      const float scalev = fc * inv + bc;
      const float aff = bf2f((unsigned int)yv[u]);
      outf[base + (size_t)t * 1024] = scalev * aff + shiftv;
    }
#pragma unroll
    for (int i = 0; i < 15; ++i) { psh[i] = csh[i + 1]; psc[i] = csc[i + 1]; }
  }
}

// ---------------------------------------------------------------------------
// Workspace layout (22 MiB, proven safe; ws_size known to be in [22,38) MiB):
//   ya  : ws + 0        16 MiB (affine, bf16)
//   Wta : ws + 16 MiB    2 MiB (Wa^T bf16)
//   Wts : ws + 18 MiB    2 MiB (Wshift^T bf16)
//   Wtc : ws + 20 MiB    2 MiB (Wscale^T bf16)
// d_out doubles as the (ysh,ysc) bf16-pair slab before filter_combine
// overwrites it in place with the final f32 output.
// ---------------------------------------------------------------------------
extern "C" void kernel_launch(void* const* d_in, const int* in_sizes, int n_in,
                              void* d_out, int out_size, void* d_ws, size_t ws_size,
                              hipStream_t stream) {
  const float* x   = (const float*)d_in[0];
  const float* Wa  = (const float*)d_in[1];
  const float* ba  = (const float*)d_in[2];
  const float* Wsh = (const float*)d_in[3];
  const float* bsh = (const float*)d_in[4];
  const float* Wsc = (const float*)d_in[5];
  const float* bsc = (const float*)d_in[6];

  char* ws = (char*)d_ws;
  unsigned short* ya  = (unsigned short*)(ws);
  unsigned short* Wta = (unsigned short*)(ws + (16u << 20));
  unsigned short* Wts = (unsigned short*)(ws + (18u << 20));
  unsigned short* Wtc = (unsigned short*)(ws + (20u << 20));

  hipLaunchKernelGGL(wconv, dim3(16, 16, 3), dim3(256), 0, stream,
                     Wa, Wsh, Wsc, Wta, Wts, Wtc);
  hipLaunchKernelGGL(fused_gemm, dim3(512), dim3(512), 0, stream,
                     x, Wta, Wts, Wtc, ba, ya, (unsigned int*)d_out);
  hipLaunchKernelGGL(filter_combine, dim3(256), dim3(512), 0, stream,
                     d_out, ya, bsh, bsc);
}

// Round 4
// 130.456 us; speedup vs baseline: 1.0001x; 1.0001x over previous
//
#include <hip/hip_runtime.h>
#include <stdint.h>

typedef __attribute__((ext_vector_type(8))) __bf16 bf16x8;
typedef __attribute__((ext_vector_type(4))) float f32x4;

__device__ __forceinline__ unsigned short f2bf(float f) {
  union { float f; unsigned int u; } v; v.f = f;
  unsigned int u = v.u;
  u = (u + 0x7FFFu + ((u >> 16) & 1u)) >> 16;   // RNE
  return (unsigned short)u;
}
__device__ __forceinline__ float bf2f(unsigned int u) {
  union { unsigned int u; float f; } v; v.u = u << 16;
  return v.f;
}

// ---------------------------------------------------------------------------
// Kernel 1: transpose + bf16-convert the three DxD weight matrices:
// Wt[n][k] = (bf16) W[k][n]  (B-operand fragments read 16B contiguous in K).
// ---------------------------------------------------------------------------
__global__ __launch_bounds__(256) void wconv(
    const float* __restrict__ Wa, const float* __restrict__ Wsh,
    const float* __restrict__ Wsc,
    unsigned short* __restrict__ Oa, unsigned short* __restrict__ Osh,
    unsigned short* __restrict__ Osc)
{
  const float* W; unsigned short* O;
  if (blockIdx.z == 0)      { W = Wa;  O = Oa; }
  else if (blockIdx.z == 1) { W = Wsh; O = Osh; }
  else                      { W = Wsc; O = Osc; }
  const int k0 = blockIdx.x * 64;
  const int n0 = blockIdx.y * 64;
  __shared__ float t[64][65];
  const int r = threadIdx.x >> 4;
  const int c4 = threadIdx.x & 15;
#pragma unroll
  for (int i = 0; i < 4; ++i) {
    const int row = r + i * 16;
    const float4 v = *(const float4*)(W + (size_t)(k0 + row) * 1024 + n0 + c4 * 4);
    t[row][c4 * 4 + 0] = v.x; t[row][c4 * 4 + 1] = v.y;
    t[row][c4 * 4 + 2] = v.z; t[row][c4 * 4 + 3] = v.w;
  }
  __syncthreads();
#pragma unroll
  for (int i = 0; i < 4; ++i) {
    const int nr = r + i * 16;
    ushort4 o;
    o.x = f2bf(t[c4 * 4 + 0][nr]);
    o.y = f2bf(t[c4 * 4 + 1][nr]);
    o.z = f2bf(t[c4 * 4 + 2][nr]);
    o.w = f2bf(t[c4 * 4 + 3][nr]);
    *(ushort4*)(O + (size_t)(n0 + nr) * 1024 + k0 + c4 * 4) = o;
  }
}

// ---------------------------------------------------------------------------
// Kernel 2: triple GEMM with SHARED A (associativity: the Gaussian row-mix
// commutes with the channel matmuls, so all three GEMMs consume x directly):
//   ya  = relu(x@Wa + ba)      -> bf16 to ws
//   ysh = x@Wsh, ysc = x@Wsc   -> packed (bf16,bf16) u32 into d_out slots
// BM=128 BN=128 BK=64, 512 thr (8 waves 2Mx4N), double-buffered LDS (128 KB),
// 2-phase: issue next tile's loads BEFORE the MFMA phase (T3-minimum recipe).
// ---------------------------------------------------------------------------
__global__ __launch_bounds__(512, 2) void fused_gemm(
    const float* __restrict__ x,
    const unsigned short* __restrict__ Wta, const unsigned short* __restrict__ Wts,
    const unsigned short* __restrict__ Wtc,
    const float* __restrict__ ba,
    unsigned short* __restrict__ ya, unsigned int* __restrict__ pk)
{
  __shared__ unsigned short sX[2][128 * 64];
  __shared__ unsigned short sA[2][128 * 64];
  __shared__ unsigned short sS[2][128 * 64];
  __shared__ unsigned short sC[2][128 * 64];

  const int tid = threadIdx.x;
  const int lane = tid & 63;
  const int wid = tid >> 6;
  const int wm = wid >> 2;
  const int wn = wid & 3;

  const int bid = blockIdx.x;        // 512 blocks
  const int bn0 = (bid & 7) * 128;   // XCD-friendly: one N column per XCD
  const int bm0 = (bid >> 3) * 128;

  // staging map (global_load_lds): physical LDS 16B slot -> (row,col), with
  // the XOR swizzle pre-applied on the GLOBAL source (rule #21).
  int rowS[2], colS[2];
#pragma unroll
  for (int p = 0; p < 2; ++p) {
    const int po = (p * 512 + tid) * 16;
    const int r = po >> 7;
    const int lo = po ^ ((r & 7) << 4);
    rowS[p] = r;
    colS[p] = (lo & 127) >> 1;
  }

  // X reg-staging map (f32 -> bf16 -> swizzled ds_write)
  const int xr0 = tid >> 4;          // 0..31
  const int xc  = (tid & 15) * 4;    // f32 col
  const int xsw = (xr0 & 7) << 4;

  const int lr = lane & 15;
  const int lk = lane >> 4;

  f32x4 accA[4][2], accS[4][2], accC[4][2];
  const f32x4 z = {0.f, 0.f, 0.f, 0.f};
#pragma unroll
  for (int m = 0; m < 4; ++m)
#pragma unroll
    for (int j = 0; j < 2; ++j) { accA[m][j] = z; accS[m][j] = z; accC[m][j] = z; }

  auto stageB = [&](int k0, int buf) {
#pragma unroll
    for (int p = 0; p < 2; ++p) {
      const size_t roff = (size_t)(bn0 + rowS[p]) * 1024 + k0 + colS[p];
      const int doff = (p * 512 + (wid << 6)) * 8;   // in us elements
      __builtin_amdgcn_global_load_lds(
          (const __attribute__((address_space(1))) void*)(Wta + roff),
          (__attribute__((address_space(3))) void*)(&sA[buf][0] + doff), 16, 0, 0);
      __builtin_amdgcn_global_load_lds(
          (const __attribute__((address_space(1))) void*)(Wts + roff),
          (__attribute__((address_space(3))) void*)(&sS[buf][0] + doff), 16, 0, 0);
      __builtin_amdgcn_global_load_lds(
          (const __attribute__((address_space(1))) void*)(Wtc + roff),
          (__attribute__((address_space(3))) void*)(&sC[buf][0] + doff), 16, 0, 0);
    }
  };
  auto writeX = [&](int buf, const float4* xv) {
#pragma unroll
    for (int i = 0; i < 4; ++i) {
      ushort4 o;
      o.x = f2bf(xv[i].x); o.y = f2bf(xv[i].y);
      o.z = f2bf(xv[i].z); o.w = f2bf(xv[i].w);
      const int row = i * 32 + xr0;
      const int po = (row * 128 + xc * 2) ^ xsw;
      *(ushort4*)((char*)&sX[buf][0] + po) = o;
    }
  };

  // prologue: stage tile 0 into buf 0
  float4 xv[4];
#pragma unroll
  for (int i = 0; i < 4; ++i)
    xv[i] = *(const float4*)(x + (size_t)(bm0 + i * 32 + xr0) * 1024 + 0 + xc);
  stageB(0, 0);
  writeX(0, xv);
  __syncthreads();   // drains vmcnt(0) + lgkmcnt(0)

  for (int kt = 0; kt < 16; ++kt) {
    const int cur = kt & 1, nxt = cur ^ 1;
    const bool pf = (kt + 1) < 16;
    if (pf) {
      const int k0n = (kt + 1) * 64;
#pragma unroll
      for (int i = 0; i < 4; ++i)
        xv[i] = *(const float4*)(x + (size_t)(bm0 + i * 32 + xr0) * 1024 + k0n + xc);
      stageB(k0n, nxt);
    }

#pragma unroll
    for (int s = 0; s < 2; ++s) {
      bf16x8 ax[4], bA[2], bS[2], bC[2];
#pragma unroll
      for (int m = 0; m < 4; ++m) {
        const int row = wm * 64 + m * 16 + lr;
        const int po = (row * 128 + (s * 32 + lk * 8) * 2) ^ ((row & 7) << 4);
        ax[m] = *(const bf16x8*)((const char*)&sX[cur][0] + po);
      }
#pragma unroll
      for (int j = 0; j < 2; ++j) {
        const int row = wn * 32 + j * 16 + lr;
        const int po = (row * 128 + (s * 32 + lk * 8) * 2) ^ ((row & 7) << 4);
        bA[j] = *(const bf16x8*)((const char*)&sA[cur][0] + po);
        bS[j] = *(const bf16x8*)((const char*)&sS[cur][0] + po);
        bC[j] = *(const bf16x8*)((const char*)&sC[cur][0] + po);
      }
      __builtin_amdgcn_s_setprio(1);
#pragma unroll
      for (int m = 0; m < 4; ++m)
#pragma unroll
        for (int j = 0; j < 2; ++j) {
          accA[m][j] = __builtin_amdgcn_mfma_f32_16x16x32_bf16(ax[m], bA[j], accA[m][j], 0, 0, 0);
          accS[m][j] = __builtin_amdgcn_mfma_f32_16x16x32_bf16(ax[m], bS[j], accS[m][j], 0, 0, 0);
          accC[m][j] = __builtin_amdgcn_mfma_f32_16x16x32_bf16(ax[m], bC[j], accC[m][j], 0, 0, 0);
        }
      __builtin_amdgcn_s_setprio(0);
    }

    if (pf) writeX(nxt, xv);   // compiler inserts the vmcnt wait for xv
    __syncthreads();           // drains vmcnt(0) (B tiles) + lgkm (X writes)
  }

  // epilogue. C/D layout: col=lane&15, row=(lane>>4)*4+reg [measured m89/m91]
#pragma unroll
  for (int j = 0; j < 2; ++j) {
    const int n = bn0 + wn * 32 + j * 16 + lr;
    const float Ba = ba[n];
#pragma unroll
    for (int m = 0; m < 4; ++m) {
      const int rbase = bm0 + wm * 64 + m * 16 + lk * 4;
#pragma unroll
      for (int r = 0; r < 4; ++r) {
        const size_t idx = (size_t)(rbase + r) * 1024 + n;
        const float aff = fmaxf(accA[m][j][r] + Ba, 0.0f);
        ya[idx] = f2bf(aff);
        pk[idx] = (unsigned int)f2bf(accS[m][j][r]) |
                  ((unsigned int)f2bf(accC[m][j][r]) << 16);
      }
    }
  }
}

// ---------------------------------------------------------------------------
// Kernel 3: causal Gaussian filter along t + combine, IN PLACE over d_out.
//   shift = filter(ysh)+bsh; scale = filter(ysc)+bsc; out = scale*ya + shift
// Each block owns one (batch, 32-col slice); 16 half-wave segments cover all
// 1024 t. Halo (15 rows) pre-read into regs before a barrier, so the f32
// overwrites never race the bf16 reads. Static 16-row window (rule #20).
// ---------------------------------------------------------------------------
__global__ __launch_bounds__(512) void filter_combine(
    void* slab,                         // d_out: read packed u32, write f32
    const unsigned short* __restrict__ ya,
    const float* __restrict__ bshift, const float* __restrict__ bscale)
{
  const unsigned int* pk = (const unsigned int*)slab;
  float* outf = (float*)slab;

  const int tid = threadIdx.x;
  const int b = blockIdx.x >> 5;            // 8 batches
  const int n0 = (blockIdx.x & 31) << 5;    // 32 col-slices
  const int lane = tid & 63;
  const int w = tid >> 6;                   // 0..7
  const int seg = (w << 1) | (lane >> 5);   // 0..15, 64 t-rows each
  const int col = lane & 31;
  const int n = n0 + col;
  const int t0 = seg * 64;
  const size_t base = (size_t)b * 1024 * 1024 + n;  // + t*1024

  float g[16];
#pragma unroll
  for (int k = 0; k < 16; ++k) g[k] = __expf(-(float)(k * k) * 0.125f);
  float nfull = 0.f;
#pragma unroll
  for (int k = 0; k < 16; ++k) nfull += g[k];
  const float invf = 1.0f / nfull;

  // halo pre-read: rows t0-15 .. t0-1 (zeros at batch start)
  float psh[15], psc[15];
#pragma unroll
  for (int i = 0; i < 15; ++i) {
    float vs = 0.f, vc = 0.f;
    if (t0 > 0) {
      const unsigned int u = pk[base + (size_t)(t0 - 15 + i) * 1024];
      vs = bf2f(u & 0xffffu); vc = bf2f(u >> 16);
    }
    psh[i] = vs; psc[i] = vc;
  }
  __syncthreads();   // all halo reads complete before any f32 overwrite

  const float bs = bshift[n];
  const float bc = bscale[n];

  for (int c = 0; c < 4; ++c) {             // 4 chunks of 16 t-rows
    const int T = t0 + c * 16;
    unsigned int cu[16];
#pragma unroll
    for (int u = 0; u < 16; ++u) cu[u] = pk[base + (size_t)(T + u) * 1024];
    unsigned short yv[16];
#pragma unroll
    for (int u = 0; u < 16; ++u) yv[u] = ya[base + (size_t)(T + u) * 1024];
    float csh[16], csc[16];
#pragma unroll
    for (int u = 0; u < 16; ++u) {
      csh[u] = bf2f(cu[u] & 0xffffu);
      csc[u] = bf2f(cu[u] >> 16);
    }
#pragma unroll
    for (int u = 0; u < 16; ++u) {
      float fs = 0.f, fc = 0.f;
#pragma unroll
      for (int k = 0; k < 16; ++k) {
        const int d = u - k;
        const float vs = (d >= 0) ? csh[d] : psh[15 + d];
        const float vc = (d >= 0) ? csc[d] : psc[15 + d];
        fs = fmaf(g[k], vs, fs);
        fc = fmaf(g[k], vc, fc);
      }
      const int t = T + u;
      float inv = invf;
      if (t < 15) {                          // batch start: partial norm
        float s = 0.f;
#pragma unroll
        for (int k = 0; k < 16; ++k) s += (k <= t) ? g[k] : 0.f;
        inv = 1.0f / s;
      }
      const float shiftv = fs * inv + bs;
      const float scalev = fc * inv + bc;
      const float aff = bf2f((unsigned int)yv[u]);
      outf[base + (size_t)t * 1024] = scalev * aff + shiftv;
    }
#pragma unroll
    for (int i = 0; i < 15; ++i) { psh[i] = csh[i + 1]; psc[i] = csc[i + 1]; }
  }
}

// ---------------------------------------------------------------------------
// Workspace layout (22 MiB, proven safe; ws_size known to be in [22,38) MiB):
//   ya  : ws + 0        16 MiB (affine, bf16)
//   Wta : ws + 16 MiB    2 MiB (Wa^T bf16)
//   Wts : ws + 18 MiB    2 MiB (Wshift^T bf16)
//   Wtc : ws + 20 MiB    2 MiB (Wscale^T bf16)
// d_out doubles as the (ysh,ysc) bf16-pair slab before filter_combine
// overwrites it in place with the final f32 output.
// ---------------------------------------------------------------------------
extern "C" void kernel_launch(void* const* d_in, const int* in_sizes, int n_in,
                              void* d_out, int out_size, void* d_ws, size_t ws_size,
                              hipStream_t stream) {
  const float* x   = (const float*)d_in[0];
  const float* Wa  = (const float*)d_in[1];
  const float* ba  = (const float*)d_in[2];
  const float* Wsh = (const float*)d_in[3];
  const float* bsh = (const float*)d_in[4];
  const float* Wsc = (const float*)d_in[5];
  const float* bsc = (const float*)d_in[6];

  char* ws = (char*)d_ws;
  unsigned short* ya  = (unsigned short*)(ws);
  unsigned short* Wta = (unsigned short*)(ws + (16u << 20));
  unsigned short* Wts = (unsigned short*)(ws + (18u << 20));
  unsigned short* Wtc = (unsigned short*)(ws + (20u << 20));

  hipLaunchKernelGGL(wconv, dim3(16, 16, 3), dim3(256), 0, stream,
                     Wa, Wsh, Wsc, Wta, Wts, Wtc);
  hipLaunchKernelGGL(fused_gemm, dim3(512), dim3(512), 0, stream,
                     x, Wta, Wts, Wtc, ba, ya, (unsigned int*)d_out);
  hipLaunchKernelGGL(filter_combine, dim3(256), dim3(512), 0, stream,
                     d_out, ya, bsh, bsc);
}

// Round 5
// 130.293 us; speedup vs baseline: 1.0013x; 1.0012x over previous
//
#include <hip/hip_runtime.h>
#include <stdint.h>

typedef __attribute__((ext_vector_type(8))) __bf16 bf16x8;
typedef __attribute__((ext_vector_type(4))) float f32x4;

__device__ __forceinline__ unsigned short f2bf(float f) {
  union { float f; unsigned int u; } v; v.f = f;
  unsigned int u = v.u;
  u = (u + 0x7FFFu + ((u >> 16) & 1u)) >> 16;   // RNE
  return (unsigned short)u;
}
__device__ __forceinline__ float bf2f(unsigned int u) {
  union { unsigned int u; float f; } v; v.u = u << 16;
  return v.f;
}

// ---------------------------------------------------------------------------
// Kernel 1: transpose + bf16-convert the three DxD weight matrices:
// Wt[n][k] = (bf16) W[k][n]  (B-operand fragments read 16B contiguous in K).
// ---------------------------------------------------------------------------
__global__ __launch_bounds__(256) void wconv(
    const float* __restrict__ Wa, const float* __restrict__ Wsh,
    const float* __restrict__ Wsc,
    unsigned short* __restrict__ Oa, unsigned short* __restrict__ Osh,
    unsigned short* __restrict__ Osc)
{
  const float* W; unsigned short* O;
  if (blockIdx.z == 0)      { W = Wa;  O = Oa; }
  else if (blockIdx.z == 1) { W = Wsh; O = Osh; }
  else                      { W = Wsc; O = Osc; }
  const int k0 = blockIdx.x * 64;
  const int n0 = blockIdx.y * 64;
  __shared__ float t[64][65];
  const int r = threadIdx.x >> 4;
  const int c4 = threadIdx.x & 15;
#pragma unroll
  for (int i = 0; i < 4; ++i) {
    const int row = r + i * 16;
    const float4 v = *(const float4*)(W + (size_t)(k0 + row) * 1024 + n0 + c4 * 4);
    t[row][c4 * 4 + 0] = v.x; t[row][c4 * 4 + 1] = v.y;
    t[row][c4 * 4 + 2] = v.z; t[row][c4 * 4 + 3] = v.w;
  }
  __syncthreads();
#pragma unroll
  for (int i = 0; i < 4; ++i) {
    const int nr = r + i * 16;
    ushort4 o;
    o.x = f2bf(t[c4 * 4 + 0][nr]);
    o.y = f2bf(t[c4 * 4 + 1][nr]);
    o.z = f2bf(t[c4 * 4 + 2][nr]);
    o.w = f2bf(t[c4 * 4 + 3][nr]);
    *(ushort4*)(O + (size_t)(n0 + nr) * 1024 + k0 + c4 * 4) = o;
  }
}

// ---------------------------------------------------------------------------
// Kernel 2: triple GEMM with SHARED A (associativity: the Gaussian row-mix
// commutes with the channel matmuls, so all three GEMMs consume x directly):
//   ya  = relu(x@Wa + ba)      -> bf16 to ws
//   ysh = x@Wsh, ysc = x@Wsc   -> packed (bf16,bf16) u32 into d_out slots
// BM=128 BN=128 BK=64, 512 thr (8 waves 2Mx4N), double-buffered LDS (128 KB),
// 2-phase: issue next tile's loads BEFORE the MFMA phase (T3-minimum recipe).
// ---------------------------------------------------------------------------
__global__ __launch_bounds__(512, 2) void fused_gemm(
    const float* __restrict__ x,
    const unsigned short* __restrict__ Wta, const unsigned short* __restrict__ Wts,
    const unsigned short* __restrict__ Wtc,
    const float* __restrict__ ba,
    unsigned short* __restrict__ ya, unsigned int* __restrict__ pk)
{
  __shared__ unsigned short sX[2][128 * 64];
  __shared__ unsigned short sA[2][128 * 64];
  __shared__ unsigned short sS[2][128 * 64];
  __shared__ unsigned short sC[2][128 * 64];

  const int tid = threadIdx.x;
  const int lane = tid & 63;
  const int wid = tid >> 6;
  const int wm = wid >> 2;
  const int wn = wid & 3;

  const int bid = blockIdx.x;        // 512 blocks
  const int bn0 = (bid & 7) * 128;   // XCD-friendly: one N column per XCD
  const int bm0 = (bid >> 3) * 128;

  // staging map (global_load_lds): physical LDS 16B slot -> (row,col), with
  // the XOR swizzle pre-applied on the GLOBAL source (rule #21).
  int rowS[2], colS[2];
#pragma unroll
  for (int p = 0; p < 2; ++p) {
    const int po = (p * 512 + tid) * 16;
    const int r = po >> 7;
    const int lo = po ^ ((r & 7) << 4);
    rowS[p] = r;
    colS[p] = (lo & 127) >> 1;
  }

  // X reg-staging map (f32 -> bf16 -> swizzled ds_write)
  const int xr0 = tid >> 4;          // 0..31
  const int xc  = (tid & 15) * 4;    // f32 col
  const int xsw = (xr0 & 7) << 4;

  const int lr = lane & 15;
  const int lk = lane >> 4;

  f32x4 accA[4][2], accS[4][2], accC[4][2];
  const f32x4 z = {0.f, 0.f, 0.f, 0.f};
#pragma unroll
  for (int m = 0; m < 4; ++m)
#pragma unroll
    for (int j = 0; j < 2; ++j) { accA[m][j] = z; accS[m][j] = z; accC[m][j] = z; }

  auto stageB = [&](int k0, int buf) {
#pragma unroll
    for (int p = 0; p < 2; ++p) {
      const size_t roff = (size_t)(bn0 + rowS[p]) * 1024 + k0 + colS[p];
      const int doff = (p * 512 + (wid << 6)) * 8;   // in us elements
      __builtin_amdgcn_global_load_lds(
          (const __attribute__((address_space(1))) void*)(Wta + roff),
          (__attribute__((address_space(3))) void*)(&sA[buf][0] + doff), 16, 0, 0);
      __builtin_amdgcn_global_load_lds(
          (const __attribute__((address_space(1))) void*)(Wts + roff),
          (__attribute__((address_space(3))) void*)(&sS[buf][0] + doff), 16, 0, 0);
      __builtin_amdgcn_global_load_lds(
          (const __attribute__((address_space(1))) void*)(Wtc + roff),
          (__attribute__((address_space(3))) void*)(&sC[buf][0] + doff), 16, 0, 0);
    }
  };
  auto writeX = [&](int buf, const float4* xv) {
#pragma unroll
    for (int i = 0; i < 4; ++i) {
      ushort4 o;
      o.x = f2bf(xv[i].x); o.y = f2bf(xv[i].y);
      o.z = f2bf(xv[i].z); o.w = f2bf(xv[i].w);
      const int row = i * 32 + xr0;
      const int po = (row * 128 + xc * 2) ^ xsw;
      *(ushort4*)((char*)&sX[buf][0] + po) = o;
    }
  };

  // prologue: stage tile 0 into buf 0
  float4 xv[4];
#pragma unroll
  for (int i = 0; i < 4; ++i)
    xv[i] = *(const float4*)(x + (size_t)(bm0 + i * 32 + xr0) * 1024 + 0 + xc);
  stageB(0, 0);
  writeX(0, xv);
  __syncthreads();   // drains vmcnt(0) + lgkmcnt(0)

  for (int kt = 0; kt < 16; ++kt) {
    const int cur = kt & 1, nxt = cur ^ 1;
    const bool pf = (kt + 1) < 16;
    if (pf) {
      const int k0n = (kt + 1) * 64;
#pragma unroll
      for (int i = 0; i < 4; ++i)
        xv[i] = *(const float4*)(x + (size_t)(bm0 + i * 32 + xr0) * 1024 + k0n + xc);
      stageB(k0n, nxt);
    }

#pragma unroll
    for (int s = 0; s < 2; ++s) {
      bf16x8 ax[4], bA[2], bS[2], bC[2];
#pragma unroll
      for (int m = 0; m < 4; ++m) {
        const int row = wm * 64 + m * 16 + lr;
        const int po = (row * 128 + (s * 32 + lk * 8) * 2) ^ ((row & 7) << 4);
        ax[m] = *(const bf16x8*)((const char*)&sX[cur][0] + po);
      }
#pragma unroll
      for (int j = 0; j < 2; ++j) {
        const int row = wn * 32 + j * 16 + lr;
        const int po = (row * 128 + (s * 32 + lk * 8) * 2) ^ ((row & 7) << 4);
        bA[j] = *(const bf16x8*)((const char*)&sA[cur][0] + po);
        bS[j] = *(const bf16x8*)((const char*)&sS[cur][0] + po);
        bC[j] = *(const bf16x8*)((const char*)&sC[cur][0] + po);
      }
      __builtin_amdgcn_s_setprio(1);
#pragma unroll
      for (int m = 0; m < 4; ++m)
#pragma unroll
        for (int j = 0; j < 2; ++j) {
          accA[m][j] = __builtin_amdgcn_mfma_f32_16x16x32_bf16(ax[m], bA[j], accA[m][j], 0, 0, 0);
          accS[m][j] = __builtin_amdgcn_mfma_f32_16x16x32_bf16(ax[m], bS[j], accS[m][j], 0, 0, 0);
          accC[m][j] = __builtin_amdgcn_mfma_f32_16x16x32_bf16(ax[m], bC[j], accC[m][j], 0, 0, 0);
        }
      __builtin_amdgcn_s_setprio(0);
    }

    if (pf) writeX(nxt, xv);   // compiler inserts the vmcnt wait for xv
    __syncthreads();           // drains vmcnt(0) (B tiles) + lgkm (X writes)
  }

  // epilogue. C/D layout: col=lane&15, row=(lane>>4)*4+reg [measured m89/m91]
#pragma unroll
  for (int j = 0; j < 2; ++j) {
    const int n = bn0 + wn * 32 + j * 16 + lr;
    const float Ba = ba[n];
#pragma unroll
    for (int m = 0; m < 4; ++m) {
      const int rbase = bm0 + wm * 64 + m * 16 + lk * 4;
#pragma unroll
      for (int r = 0; r < 4; ++r) {
        const size_t idx = (size_t)(rbase + r) * 1024 + n;
        const float aff = fmaxf(accA[m][j][r] + Ba, 0.0f);
        ya[idx] = f2bf(aff);
        pk[idx] = (unsigned int)f2bf(accS[m][j][r]) |
                  ((unsigned int)f2bf(accC[m][j][r]) << 16);
      }
    }
  }
}

// ---------------------------------------------------------------------------
// Kernel 3: causal Gaussian filter along t + combine, IN PLACE over d_out.
//   shift = filter(ysh)+bsh; scale = filter(ysc)+bsc; out = scale*ya + shift
// Each block owns one (batch, 32-col slice); 16 half-wave segments cover all
// 1024 t. Halo (15 rows) pre-read into regs before a barrier, so the f32
// overwrites never race the bf16 reads. Static 16-row window (rule #20).
// ---------------------------------------------------------------------------
__global__ __launch_bounds__(512) void filter_combine(
    void* slab,                         // d_out: read packed u32, write f32
    const unsigned short* __restrict__ ya,
    const float* __restrict__ bshift, const float* __restrict__ bscale)
{
  const unsigned int* pk = (const unsigned int*)slab;
  float* outf = (float*)slab;

  const int tid = threadIdx.x;
  const int b = blockIdx.x >> 5;            // 8 batches
  const int n0 = (blockIdx.x & 31) << 5;    // 32 col-slices
  const int lane = tid & 63;
  const int w = tid >> 6;                   // 0..7
  const int seg = (w << 1) | (lane >> 5);   // 0..15, 64 t-rows each
  const int col = lane & 31;
  const int n = n0 + col;
  const int t0 = seg * 64;
  const size_t base = (size_t)b * 1024 * 1024 + n;  // + t*1024

  float g[16];
#pragma unroll
  for (int k = 0; k < 16; ++k) g[k] = __expf(-(float)(k * k) * 0.125f);
  float nfull = 0.f;
#pragma unroll
  for (int k = 0; k < 16; ++k) nfull += g[k];
  const float invf = 1.0f / nfull;

  // halo pre-read: rows t0-15 .. t0-1 (zeros at batch start)
  float psh[15], psc[15];
#pragma unroll
  for (int i = 0; i < 15; ++i) {
    float vs = 0.f, vc = 0.f;
    if (t0 > 0) {
      const unsigned int u = pk[base + (size_t)(t0 - 15 + i) * 1024];
      vs = bf2f(u & 0xffffu); vc = bf2f(u >> 16);
    }
    psh[i] = vs; psc[i] = vc;
  }
  __syncthreads();   // all halo reads complete before any f32 overwrite

  const float bs = bshift[n];
  const float bc = bscale[n];

  for (int c = 0; c < 4; ++c) {             // 4 chunks of 16 t-rows
    const int T = t0 + c * 16;
    unsigned int cu[16];
#pragma unroll
    for (int u = 0; u < 16; ++u) cu[u] = pk[base + (size_t)(T + u) * 1024];
    unsigned short yv[16];
#pragma unroll
    for (int u = 0; u < 16; ++u) yv[u] = ya[base + (size_t)(T + u) * 1024];
    float csh[16], csc[16];
#pragma unroll
    for (int u = 0; u < 16; ++u) {
      csh[u] = bf2f(cu[u] & 0xffffu);
      csc[u] = bf2f(cu[u] >> 16);
    }
#pragma unroll
    for (int u = 0; u < 16; ++u) {
      float fs = 0.f, fc = 0.f;
#pragma unroll
      for (int k = 0; k < 16; ++k) {
        const int d = u - k;
        const float vs = (d >= 0) ? csh[d] : psh[15 + d];
        const float vc = (d >= 0) ? csc[d] : psc[15 + d];
        fs = fmaf(g[k], vs, fs);
        fc = fmaf(g[k], vc, fc);
      }
      const int t = T + u;
      float inv = invf;
      if (t < 15) {                          // batch start: partial norm
        float s = 0.f;
#pragma unroll
        for (int k = 0; k < 16; ++k) s += (k <= t) ? g[k] : 0.f;
        inv = 1.0f / s;
      }
      const float shiftv = fs * inv + bs;
      const float scalev = fc * inv + bc;
      const float aff = bf2f((unsigned int)yv[u]);
      outf[base + (size_t)t * 1024] = scalev * aff + shiftv;
    }
#pragma unroll
    for (int i = 0; i < 15; ++i) { psh[i] = csh[i + 1]; psc[i] = csc[i + 1]; }
  }
}

// ---------------------------------------------------------------------------
// Workspace layout (22 MiB, proven safe; ws_size known to be in [22,38) MiB):
//   ya  : ws + 0        16 MiB (affine, bf16)
//   Wta : ws + 16 MiB    2 MiB (Wa^T bf16)
//   Wts : ws + 18 MiB    2 MiB (Wshift^T bf16)
//   Wtc : ws + 20 MiB    2 MiB (Wscale^T bf16)
// d_out doubles as the (ysh,ysc) bf16-pair slab before filter_combine
// overwrites it in place with the final f32 output.
// ---------------------------------------------------------------------------
extern "C" void kernel_launch(void* const* d_in, const int* in_sizes, int n_in,
                              void* d_out, int out_size, void* d_ws, size_t ws_size,
                              hipStream_t stream) {
  const float* x   = (const float*)d_in[0];
  const float* Wa  = (const float*)d_in[1];
  const float* ba  = (const float*)d_in[2];
  const float* Wsh = (const float*)d_in[3];
  const float* bsh = (const float*)d_in[4];
  const float* Wsc = (const float*)d_in[5];
  const float* bsc = (const float*)d_in[6];

  char* ws = (char*)d_ws;
  unsigned short* ya  = (unsigned short*)(ws);
  unsigned short* Wta = (unsigned short*)(ws + (16u << 20));
  unsigned short* Wts = (unsigned short*)(ws + (18u << 20));
  unsigned short* Wtc = (unsigned short*)(ws + (20u << 20));

  hipLaunchKernelGGL(wconv, dim3(16, 16, 3), dim3(256), 0, stream,
                     Wa, Wsh, Wsc, Wta, Wts, Wtc);
  hipLaunchKernelGGL(fused_gemm, dim3(512), dim3(512), 0, stream,
                     x, Wta, Wts, Wtc, ba, ya, (unsigned int*)d_out);
  hipLaunchKernelGGL(filter_combine, dim3(256), dim3(512), 0, stream,
                     d_out, ya, bsh, bsc);
}

// Round 6
// 120.623 us; speedup vs baseline: 1.0816x; 1.0802x over previous
//
#include <hip/hip_runtime.h>
#include <stdint.h>

typedef __attribute__((ext_vector_type(8))) __bf16 bf16x8;
typedef __attribute__((ext_vector_type(4))) float f32x4;

__device__ __forceinline__ unsigned short f2bf(float f) {
  union { float f; unsigned int u; } v; v.f = f;
  unsigned int u = v.u;
  u = (u + 0x7FFFu + ((u >> 16) & 1u)) >> 16;   // RNE
  return (unsigned short)u;
}
__device__ __forceinline__ float bf2f(unsigned int u) {
  union { unsigned int u; float f; } v; v.u = u << 16;
  return v.f;
}

// ---------------------------------------------------------------------------
// Kernel 1: transpose + bf16-convert the three DxD weight matrices:
// Wt[n][k] = (bf16) W[k][n]  (B-operand fragments read 16B contiguous in K).
// ---------------------------------------------------------------------------
__global__ __launch_bounds__(256) void wconv(
    const float* __restrict__ Wa, const float* __restrict__ Wsh,
    const float* __restrict__ Wsc,
    unsigned short* __restrict__ Oa, unsigned short* __restrict__ Osh,
    unsigned short* __restrict__ Osc)
{
  const float* W; unsigned short* O;
  if (blockIdx.z == 0)      { W = Wa;  O = Oa; }
  else if (blockIdx.z == 1) { W = Wsh; O = Osh; }
  else                      { W = Wsc; O = Osc; }
  const int k0 = blockIdx.x * 64;
  const int n0 = blockIdx.y * 64;
  __shared__ float t[64][65];
  const int r = threadIdx.x >> 4;
  const int c4 = threadIdx.x & 15;
#pragma unroll
  for (int i = 0; i < 4; ++i) {
    const int row = r + i * 16;
    const float4 v = *(const float4*)(W + (size_t)(k0 + row) * 1024 + n0 + c4 * 4);
    t[row][c4 * 4 + 0] = v.x; t[row][c4 * 4 + 1] = v.y;
    t[row][c4 * 4 + 2] = v.z; t[row][c4 * 4 + 3] = v.w;
  }
  __syncthreads();
#pragma unroll
  for (int i = 0; i < 4; ++i) {
    const int nr = r + i * 16;
    ushort4 o;
    o.x = f2bf(t[c4 * 4 + 0][nr]);
    o.y = f2bf(t[c4 * 4 + 1][nr]);
    o.z = f2bf(t[c4 * 4 + 2][nr]);
    o.w = f2bf(t[c4 * 4 + 3][nr]);
    *(ushort4*)(O + (size_t)(n0 + nr) * 1024 + k0 + c4 * 4) = o;
  }
}

// ---------------------------------------------------------------------------
// Kernel 2: triple GEMM, shared A. R5 post-mortem: old 128x128x64 tiling was
// LDS-BW-bound (224 KB LDS traffic vs 1546 MFMA cyc per K-step -> MfmaUtil
// 20%). New geometry: BM=256 BN=128 BK=32, 8 waves 2Mx4N, wave tile 128x32
// (minimizes Mw+3*Nw at the 192-acc-reg budget): per K-step/CU = 112 KB read
// + 40 KB write vs 1546 MFMA cyc -> MFMA-bound. Row stride 64B -> swizzle
// swz(row)=((row>>1)&3)<<4, applied on gload_lds SOURCE + ds_write + ds_read
// (rule #21). dbuf LDS 80 KB, 256 blocks (1/CU).
//   ya  = relu(x@Wa + ba)      -> bf16 to ws
//   ysh = x@Wsh, ysc = x@Wsc   -> packed (bf16,bf16) u32 into d_out slots
// ---------------------------------------------------------------------------
__global__ __launch_bounds__(512, 2) void fused_gemm(
    const float* __restrict__ x,
    const unsigned short* __restrict__ Wta, const unsigned short* __restrict__ Wts,
    const unsigned short* __restrict__ Wtc,
    const float* __restrict__ ba,
    unsigned short* __restrict__ ya, unsigned int* __restrict__ pk)
{
  __shared__ unsigned short sX[2][256 * 32];   // 2 x 16 KB
  __shared__ unsigned short sA[2][128 * 32];   // 2 x  8 KB
  __shared__ unsigned short sS[2][128 * 32];
  __shared__ unsigned short sC[2][128 * 32];

  const int tid = threadIdx.x;
  const int lane = tid & 63;
  const int wid = tid >> 6;      // 0..7
  const int wm = wid >> 2;       // 0..1 (M half: 128 rows)
  const int wn = wid & 3;        // 0..3 (N quarter: 32 cols)

  const int bid = blockIdx.x;        // 256 blocks
  const int bn0 = (bid & 7) * 128;   // XCD c owns N column c (768 KB of W in L2)
  const int bm0 = (bid >> 3) * 256;

  // --- B staging map (gload_lds, wave-linear dest; swizzle via SOURCE) ---
  // wave w stages rows [w*16, w*16+16); lane l -> row w*16+(l>>2),
  // phys colbyte (l&3)*16, logical colbyte = phys ^ swz(row).
  const int wrow  = wid * 16 + (lane >> 2);                        // 0..127
  const int gcolB = ((lane & 3) * 8) ^ (((wrow >> 1) & 3) * 8);    // bf16 units

  // --- X staging map (f32 -> bf16 -> swizzled ds_write) ---
  // round i covers rows [i*64, i*64+64); thread -> row i*64+(tid>>3),
  // f32 col (tid&7)*4 (8 threads x 16B = one 128B row: fully coalesced).
  const int xr0 = tid >> 3;          // 0..63
  const int xcf = (tid & 7) * 4;     // f32 col
  const int xcb = xcf * 2;           // bf16 byte col (0..56)

  const int lr = lane & 15;          // frag col/row within 16
  const int lk = lane >> 4;          // 0..3: k-octet

  f32x4 accA[8][2], accS[8][2], accC[8][2];   // 192 regs
  const f32x4 z = {0.f, 0.f, 0.f, 0.f};
#pragma unroll
  for (int m = 0; m < 8; ++m)
#pragma unroll
    for (int j = 0; j < 2; ++j) { accA[m][j] = z; accS[m][j] = z; accC[m][j] = z; }

  auto stageB = [&](int k0, int buf) {
    const size_t roff = (size_t)(bn0 + wrow) * 1024 + k0 + gcolB;
    const int doff = wid * 512;   // ushorts (1 KB per wave)
    __builtin_amdgcn_global_load_lds(
        (const __attribute__((address_space(1))) void*)(Wta + roff),
        (__attribute__((address_space(3))) void*)(&sA[buf][0] + doff), 16, 0, 0);
    __builtin_amdgcn_global_load_lds(
        (const __attribute__((address_space(1))) void*)(Wts + roff),
        (__attribute__((address_space(3))) void*)(&sS[buf][0] + doff), 16, 0, 0);
    __builtin_amdgcn_global_load_lds(
        (const __attribute__((address_space(1))) void*)(Wtc + roff),
        (__attribute__((address_space(3))) void*)(&sC[buf][0] + doff), 16, 0, 0);
  };
  auto loadX = [&](int k0, float4* xv) {
#pragma unroll
    for (int i = 0; i < 4; ++i)
      xv[i] = *(const float4*)(x + (size_t)(bm0 + i * 64 + xr0) * 1024 + k0 + xcf);
  };
  auto writeX = [&](int buf, const float4* xv) {
#pragma unroll
    for (int i = 0; i < 4; ++i) {
      ushort4 o;
      o.x = f2bf(xv[i].x); o.y = f2bf(xv[i].y);
      o.z = f2bf(xv[i].z); o.w = f2bf(xv[i].w);
      const int row = i * 64 + xr0;
      const int po = row * 64 + (xcb ^ (((row >> 1) & 3) << 4));
      *(ushort4*)((char*)&sX[buf][0] + po) = o;
    }
  };

  // prologue
  float4 xv[4];
  loadX(0, xv);
  stageB(0, 0);
  writeX(0, xv);
  __syncthreads();

  for (int kt = 0; kt < 32; ++kt) {
    const int cur = kt & 1, nxt = cur ^ 1;
    const bool pf = (kt + 1) < 32;
    if (pf) {
      loadX((kt + 1) * 32, xv);
      stageB((kt + 1) * 32, nxt);
    }

    // B fragments (6 reads), then 8 x {1 A read, 6 MFMAs}
    bf16x8 bA[2], bS[2], bC[2];
#pragma unroll
    for (int j = 0; j < 2; ++j) {
      const int row = wn * 32 + j * 16 + lr;
      const int po = row * 64 + ((lk * 16) ^ (((row >> 1) & 3) << 4));
      bA[j] = *(const bf16x8*)((const char*)&sA[cur][0] + po);
      bS[j] = *(const bf16x8*)((const char*)&sS[cur][0] + po);
      bC[j] = *(const bf16x8*)((const char*)&sC[cur][0] + po);
    }
    __builtin_amdgcn_s_setprio(1);
#pragma unroll
    for (int m = 0; m < 8; ++m) {
      const int row = wm * 128 + m * 16 + lr;
      const int po = row * 64 + ((lk * 16) ^ (((row >> 1) & 3) << 4));
      const bf16x8 ax = *(const bf16x8*)((const char*)&sX[cur][0] + po);
#pragma unroll
      for (int j = 0; j < 2; ++j) {
        accA[m][j] = __builtin_amdgcn_mfma_f32_16x16x32_bf16(ax, bA[j], accA[m][j], 0, 0, 0);
        accS[m][j] = __builtin_amdgcn_mfma_f32_16x16x32_bf16(ax, bS[j], accS[m][j], 0, 0, 0);
        accC[m][j] = __builtin_amdgcn_mfma_f32_16x16x32_bf16(ax, bC[j], accC[m][j], 0, 0, 0);
      }
    }
    __builtin_amdgcn_s_setprio(0);

    if (pf) writeX(nxt, xv);   // compiler inserts the vmcnt wait for xv
    __syncthreads();           // buffers swap
  }

  // epilogue. C/D layout: col=lane&15, row=(lane>>4)*4+reg [measured m89/m91]
#pragma unroll
  for (int j = 0; j < 2; ++j) {
    const int n = bn0 + wn * 32 + j * 16 + lr;
    const float Ba = ba[n];
#pragma unroll
    for (int m = 0; m < 8; ++m) {
      const int rbase = bm0 + wm * 128 + m * 16 + lk * 4;
#pragma unroll
      for (int r = 0; r < 4; ++r) {
        const size_t idx = (size_t)(rbase + r) * 1024 + n;
        const float aff = fmaxf(accA[m][j][r] + Ba, 0.0f);
        ya[idx] = f2bf(aff);
        pk[idx] = (unsigned int)f2bf(accS[m][j][r]) |
                  ((unsigned int)f2bf(accC[m][j][r]) << 16);
      }
    }
  }
}

// ---------------------------------------------------------------------------
// Kernel 3: causal Gaussian filter along t + combine, IN PLACE over d_out.
//   shift = filter(ysh)+bsh; scale = filter(ysc)+bsc; out = scale*ya + shift
// Each block owns one (batch, 32-col slice); halo pre-read into regs before a
// barrier so f32 overwrites never race bf16 reads. Static indexing (rule #20).
// ---------------------------------------------------------------------------
__global__ __launch_bounds__(512) void filter_combine(
    void* slab,                         // d_out: read packed u32, write f32
    const unsigned short* __restrict__ ya,
    const float* __restrict__ bshift, const float* __restrict__ bscale)
{
  const unsigned int* pk = (const unsigned int*)slab;
  float* outf = (float*)slab;

  const int tid = threadIdx.x;
  const int b = blockIdx.x >> 5;            // 8 batches
  const int n0 = (blockIdx.x & 31) << 5;    // 32 col-slices
  const int lane = tid & 63;
  const int w = tid >> 6;                   // 0..7
  const int seg = (w << 1) | (lane >> 5);   // 0..15, 64 t-rows each
  const int col = lane & 31;
  const int n = n0 + col;
  const int t0 = seg * 64;
  const size_t base = (size_t)b * 1024 * 1024 + n;  // + t*1024

  float g[16];
#pragma unroll
  for (int k = 0; k < 16; ++k) g[k] = __expf(-(float)(k * k) * 0.125f);
  float nfull = 0.f;
#pragma unroll
  for (int k = 0; k < 16; ++k) nfull += g[k];
  const float invf = 1.0f / nfull;

  // halo pre-read: rows t0-15 .. t0-1 (zeros at batch start)
  float psh[15], psc[15];
#pragma unroll
  for (int i = 0; i < 15; ++i) {
    float vs = 0.f, vc = 0.f;
    if (t0 > 0) {
      const unsigned int u = pk[base + (size_t)(t0 - 15 + i) * 1024];
      vs = bf2f(u & 0xffffu); vc = bf2f(u >> 16);
    }
    psh[i] = vs; psc[i] = vc;
  }
  __syncthreads();   // all halo reads complete before any f32 overwrite

  const float bs = bshift[n];
  const float bc = bscale[n];

  for (int c = 0; c < 4; ++c) {             // 4 chunks of 16 t-rows
    const int T = t0 + c * 16;
    unsigned int cu[16];
#pragma unroll
    for (int u = 0; u < 16; ++u) cu[u] = pk[base + (size_t)(T + u) * 1024];
    unsigned short yv[16];
#pragma unroll
    for (int u = 0; u < 16; ++u) yv[u] = ya[base + (size_t)(T + u) * 1024];
    float csh[16], csc[16];
#pragma unroll
    for (int u = 0; u < 16; ++u) {
      csh[u] = bf2f(cu[u] & 0xffffu);
      csc[u] = bf2f(cu[u] >> 16);
    }
#pragma unroll
    for (int u = 0; u < 16; ++u) {
      float fs = 0.f, fc = 0.f;
#pragma unroll
      for (int k = 0; k < 16; ++k) {
        const int d = u - k;
        const float vs = (d >= 0) ? csh[d] : psh[15 + d];
        const float vc = (d >= 0) ? csc[d] : psc[15 + d];
        fs = fmaf(g[k], vs, fs);
        fc = fmaf(g[k], vc, fc);
      }
      const int t = T + u;
      float inv = invf;
      if (t < 15) {                          // batch start: partial norm
        float s = 0.f;
#pragma unroll
        for (int k = 0; k < 16; ++k) s += (k <= t) ? g[k] : 0.f;
        inv = 1.0f / s;
      }
      const float shiftv = fs * inv + bs;
      const float scalev = fc * inv + bc;
      const float aff = bf2f((unsigned int)yv[u]);
      outf[base + (size_t)t * 1024] = scalev * aff + shiftv;
    }
#pragma unroll
    for (int i = 0; i < 15; ++i) { psh[i] = csh[i + 1]; psc[i] = csc[i + 1]; }
  }
}

// ---------------------------------------------------------------------------
// Workspace layout (22 MiB, proven safe; ws_size known to be in [22,38) MiB):
//   ya  : ws + 0        16 MiB (affine, bf16)
//   Wta : ws + 16 MiB    2 MiB (Wa^T bf16)
//   Wts : ws + 18 MiB    2 MiB (Wshift^T bf16)
//   Wtc : ws + 20 MiB    2 MiB (Wscale^T bf16)
// d_out doubles as the (ysh,ysc) bf16-pair slab before filter_combine
// overwrites it in place with the final f32 output.
// ---------------------------------------------------------------------------
extern "C" void kernel_launch(void* const* d_in, const int* in_sizes, int n_in,
                              void* d_out, int out_size, void* d_ws, size_t ws_size,
                              hipStream_t stream) {
  const float* x   = (const float*)d_in[0];
  const float* Wa  = (const float*)d_in[1];
  const float* ba  = (const float*)d_in[2];
  const float* Wsh = (const float*)d_in[3];
  const float* bsh = (const float*)d_in[4];
  const float* Wsc = (const float*)d_in[5];
  const float* bsc = (const float*)d_in[6];

  char* ws = (char*)d_ws;
  unsigned short* ya  = (unsigned short*)(ws);
  unsigned short* Wta = (unsigned short*)(ws + (16u << 20));
  unsigned short* Wts = (unsigned short*)(ws + (18u << 20));
  unsigned short* Wtc = (unsigned short*)(ws + (20u << 20));

  hipLaunchKernelGGL(wconv, dim3(16, 16, 3), dim3(256), 0, stream,
                     Wa, Wsh, Wsc, Wta, Wts, Wtc);
  hipLaunchKernelGGL(fused_gemm, dim3(256), dim3(512), 0, stream,
                     x, Wta, Wts, Wtc, ba, ya, (unsigned int*)d_out);
  hipLaunchKernelGGL(filter_combine, dim3(256), dim3(512), 0, stream,
                     d_out, ya, bsh, bsc);
}

// Round 7
// 117.096 us; speedup vs baseline: 1.1142x; 1.0301x over previous
//
#include <hip/hip_runtime.h>
#include <stdint.h>

typedef __attribute__((ext_vector_type(8))) __bf16 bf16x8;
typedef __attribute__((ext_vector_type(4))) float f32x4;

__device__ __forceinline__ unsigned short f2bf(float f) {
  union { float f; unsigned int u; } v; v.f = f;
  unsigned int u = v.u;
  u = (u + 0x7FFFu + ((u >> 16) & 1u)) >> 16;   // RNE
  return (unsigned short)u;
}
__device__ __forceinline__ float bf2f(unsigned int u) {
  union { unsigned int u; float f; } v; v.u = u << 16;
  return v.f;
}

// ---------------------------------------------------------------------------
// Kernel 1: transpose + bf16-convert the three DxD weight matrices:
// Wt[n][k] = (bf16) W[k][n]  (B-operand fragments read 16B contiguous in K).
// ---------------------------------------------------------------------------
__global__ __launch_bounds__(256) void wconv(
    const float* __restrict__ Wa, const float* __restrict__ Wsh,
    const float* __restrict__ Wsc,
    unsigned short* __restrict__ Oa, unsigned short* __restrict__ Osh,
    unsigned short* __restrict__ Osc)
{
  const float* W; unsigned short* O;
  if (blockIdx.z == 0)      { W = Wa;  O = Oa; }
  else if (blockIdx.z == 1) { W = Wsh; O = Osh; }
  else                      { W = Wsc; O = Osc; }
  const int k0 = blockIdx.x * 64;
  const int n0 = blockIdx.y * 64;
  __shared__ float t[64][65];
  const int r = threadIdx.x >> 4;
  const int c4 = threadIdx.x & 15;
#pragma unroll
  for (int i = 0; i < 4; ++i) {
    const int row = r + i * 16;
    const float4 v = *(const float4*)(W + (size_t)(k0 + row) * 1024 + n0 + c4 * 4);
    t[row][c4 * 4 + 0] = v.x; t[row][c4 * 4 + 1] = v.y;
    t[row][c4 * 4 + 2] = v.z; t[row][c4 * 4 + 3] = v.w;
  }
  __syncthreads();
#pragma unroll
  for (int i = 0; i < 4; ++i) {
    const int nr = r + i * 16;
    ushort4 o;
    o.x = f2bf(t[c4 * 4 + 0][nr]);
    o.y = f2bf(t[c4 * 4 + 1][nr]);
    o.z = f2bf(t[c4 * 4 + 2][nr]);
    o.w = f2bf(t[c4 * 4 + 3][nr]);
    *(ushort4*)(O + (size_t)(n0 + nr) * 1024 + k0 + c4 * 4) = o;
  }
}

// ---------------------------------------------------------------------------
// Kernel 2: triple GEMM, shared A (Gaussian row-mix commutes with channel
// matmuls, so all three GEMMs consume x directly).
// R6 post-mortem: HBM-bound via bad XCD locality -- bn0=(bid&7) scattered the
// 8 blocks sharing an x-slice across 8 XCDs, so every XCD streamed all 32 MB
// of x through its 4 MB L2 (256 MB demand, 137 MB HBM, 1.9 TB/s effective,
// K-step period 7500 cyc vs 480 cyc of MFMA).
// R7 fix: XCD-OWNERSHIP REMAP. bid = c + 8n + 64g (c = XCD, round-robin):
//   bm0 = (c + 8g)*256   -> each x slice owned by exactly ONE XCD,
//   bn0 = n*128          -> its 8 N-consumers are co-resident on that XCD.
// x is HBM-fetched once (32 MB); 7/8 of X-loads become L2 hits. Geometry
// unchanged from R6: BM=256 BN=128 BK=32, 8 waves 2Mx4N (wave 128x32),
// dbuf LDS 80 KB, swizzle swz(row)=((row>>1)&3)<<4 on gload_lds SOURCE +
// ds_write + ds_read (rule #21).
//   ya  = relu(x@Wa + ba)      -> bf16 to ws
//   ysh = x@Wsh, ysc = x@Wsc   -> packed (bf16,bf16) u32 into d_out slots
// ---------------------------------------------------------------------------
__global__ __launch_bounds__(512, 2) void fused_gemm(
    const float* __restrict__ x,
    const unsigned short* __restrict__ Wta, const unsigned short* __restrict__ Wts,
    const unsigned short* __restrict__ Wtc,
    const float* __restrict__ ba,
    unsigned short* __restrict__ ya, unsigned int* __restrict__ pk)
{
  __shared__ unsigned short sX[2][256 * 32];   // 2 x 16 KB
  __shared__ unsigned short sA[2][128 * 32];   // 2 x  8 KB
  __shared__ unsigned short sS[2][128 * 32];
  __shared__ unsigned short sC[2][128 * 32];

  const int tid = threadIdx.x;
  const int lane = tid & 63;
  const int wid = tid >> 6;      // 0..7
  const int wm = wid >> 2;       // 0..1 (M half: 128 rows)
  const int wn = wid & 3;        // 0..3 (N quarter: 32 cols)

  const int bid = blockIdx.x;        // 256 blocks = 32 M-tiles x 8 N-tiles
  const int xcd = bid & 7;           // XCD id under round-robin dispatch
  const int ntl = (bid >> 3) & 7;    // N tile (co-resident on this XCD)
  const int mg  = bid >> 6;          // M group 0..3
  const int bm0 = (xcd + (mg << 3)) * 256;   // each bm0 owned by ONE XCD
  const int bn0 = ntl * 128;

  // --- B staging map (gload_lds, wave-linear dest; swizzle via SOURCE) ---
  const int wrow  = wid * 16 + (lane >> 2);                        // 0..127
  const int gcolB = ((lane & 3) * 8) ^ (((wrow >> 1) & 3) * 8);    // bf16 units

  // --- X staging map (f32 -> bf16 -> swizzled ds_write) ---
  const int xr0 = tid >> 3;          // 0..63
  const int xcf = (tid & 7) * 4;     // f32 col
  const int xcb = xcf * 2;           // bf16 byte col (0..56)

  const int lr = lane & 15;          // frag col/row within 16
  const int lk = lane >> 4;          // 0..3: k-octet

  f32x4 accA[8][2], accS[8][2], accC[8][2];
  const f32x4 z = {0.f, 0.f, 0.f, 0.f};
#pragma unroll
  for (int m = 0; m < 8; ++m)
#pragma unroll
    for (int j = 0; j < 2; ++j) { accA[m][j] = z; accS[m][j] = z; accC[m][j] = z; }

  auto stageB = [&](int k0, int buf) {
    const size_t roff = (size_t)(bn0 + wrow) * 1024 + k0 + gcolB;
    const int doff = wid * 512;   // ushorts (1 KB per wave)
    __builtin_amdgcn_global_load_lds(
        (const __attribute__((address_space(1))) void*)(Wta + roff),
        (__attribute__((address_space(3))) void*)(&sA[buf][0] + doff), 16, 0, 0);
    __builtin_amdgcn_global_load_lds(
        (const __attribute__((address_space(1))) void*)(Wts + roff),
        (__attribute__((address_space(3))) void*)(&sS[buf][0] + doff), 16, 0, 0);
    __builtin_amdgcn_global_load_lds(
        (const __attribute__((address_space(1))) void*)(Wtc + roff),
        (__attribute__((address_space(3))) void*)(&sC[buf][0] + doff), 16, 0, 0);
  };
  auto loadX = [&](int k0, float4* xv) {
#pragma unroll
    for (int i = 0; i < 4; ++i)
      xv[i] = *(const float4*)(x + (size_t)(bm0 + i * 64 + xr0) * 1024 + k0 + xcf);
  };
  auto writeX = [&](int buf, const float4* xv) {
#pragma unroll
    for (int i = 0; i < 4; ++i) {
      ushort4 o;
      o.x = f2bf(xv[i].x); o.y = f2bf(xv[i].y);
      o.z = f2bf(xv[i].z); o.w = f2bf(xv[i].w);
      const int row = i * 64 + xr0;
      const int po = row * 64 + (xcb ^ (((row >> 1) & 3) << 4));
      *(ushort4*)((char*)&sX[buf][0] + po) = o;
    }
  };

  // prologue
  float4 xv[4];
  loadX(0, xv);
  stageB(0, 0);
  writeX(0, xv);
  __syncthreads();

  for (int kt = 0; kt < 32; ++kt) {
    const int cur = kt & 1, nxt = cur ^ 1;
    const bool pf = (kt + 1) < 32;
    if (pf) {
      loadX((kt + 1) * 32, xv);
      stageB((kt + 1) * 32, nxt);
    }

    // B fragments (6 reads), then 8 x {1 A read, 6 MFMAs}
    bf16x8 bA[2], bS[2], bC[2];
#pragma unroll
    for (int j = 0; j < 2; ++j) {
      const int row = wn * 32 + j * 16 + lr;
      const int po = row * 64 + ((lk * 16) ^ (((row >> 1) & 3) << 4));
      bA[j] = *(const bf16x8*)((const char*)&sA[cur][0] + po);
      bS[j] = *(const bf16x8*)((const char*)&sS[cur][0] + po);
      bC[j] = *(const bf16x8*)((const char*)&sC[cur][0] + po);
    }
    __builtin_amdgcn_s_setprio(1);
#pragma unroll
    for (int m = 0; m < 8; ++m) {
      const int row = wm * 128 + m * 16 + lr;
      const int po = row * 64 + ((lk * 16) ^ (((row >> 1) & 3) << 4));
      const bf16x8 ax = *(const bf16x8*)((const char*)&sX[cur][0] + po);
#pragma unroll
      for (int j = 0; j < 2; ++j) {
        accA[m][j] = __builtin_amdgcn_mfma_f32_16x16x32_bf16(ax, bA[j], accA[m][j], 0, 0, 0);
        accS[m][j] = __builtin_amdgcn_mfma_f32_16x16x32_bf16(ax, bS[j], accS[m][j], 0, 0, 0);
        accC[m][j] = __builtin_amdgcn_mfma_f32_16x16x32_bf16(ax, bC[j], accC[m][j], 0, 0, 0);
      }
    }
    __builtin_amdgcn_s_setprio(0);

    if (pf) writeX(nxt, xv);   // compiler inserts the vmcnt wait for xv
    __syncthreads();           // buffers swap
  }

  // epilogue. C/D layout: col=lane&15, row=(lane>>4)*4+reg [measured m89/m91]
#pragma unroll
  for (int j = 0; j < 2; ++j) {
    const int n = bn0 + wn * 32 + j * 16 + lr;
    const float Ba = ba[n];
#pragma unroll
    for (int m = 0; m < 8; ++m) {
      const int rbase = bm0 + wm * 128 + m * 16 + lk * 4;
#pragma unroll
      for (int r = 0; r < 4; ++r) {
        const size_t idx = (size_t)(rbase + r) * 1024 + n;
        const float aff = fmaxf(accA[m][j][r] + Ba, 0.0f);
        ya[idx] = f2bf(aff);
        pk[idx] = (unsigned int)f2bf(accS[m][j][r]) |
                  ((unsigned int)f2bf(accC[m][j][r]) << 16);
      }
    }
  }
}

// ---------------------------------------------------------------------------
// Kernel 3: causal Gaussian filter along t + combine, IN PLACE over d_out.
//   shift = filter(ysh)+bsh; scale = filter(ysc)+bsc; out = scale*ya + shift
// Each block owns one (batch, 32-col slice); halo pre-read into regs before a
// barrier so f32 overwrites never race bf16 reads. Static indexing (rule #20).
// ---------------------------------------------------------------------------
__global__ __launch_bounds__(512) void filter_combine(
    void* slab,                         // d_out: read packed u32, write f32
    const unsigned short* __restrict__ ya,
    const float* __restrict__ bshift, const float* __restrict__ bscale)
{
  const unsigned int* pk = (const unsigned int*)slab;
  float* outf = (float*)slab;

  const int tid = threadIdx.x;
  const int b = blockIdx.x >> 5;            // 8 batches
  const int n0 = (blockIdx.x & 31) << 5;    // 32 col-slices
  const int lane = tid & 63;
  const int w = tid >> 6;                   // 0..7
  const int seg = (w << 1) | (lane >> 5);   // 0..15, 64 t-rows each
  const int col = lane & 31;
  const int n = n0 + col;
  const int t0 = seg * 64;
  const size_t base = (size_t)b * 1024 * 1024 + n;  // + t*1024

  float g[16];
#pragma unroll
  for (int k = 0; k < 16; ++k) g[k] = __expf(-(float)(k * k) * 0.125f);
  float nfull = 0.f;
#pragma unroll
  for (int k = 0; k < 16; ++k) nfull += g[k];
  const float invf = 1.0f / nfull;

  // halo pre-read: rows t0-15 .. t0-1 (zeros at batch start)
  float psh[15], psc[15];
#pragma unroll
  for (int i = 0; i < 15; ++i) {
    float vs = 0.f, vc = 0.f;
    if (t0 > 0) {
      const unsigned int u = pk[base + (size_t)(t0 - 15 + i) * 1024];
      vs = bf2f(u & 0xffffu); vc = bf2f(u >> 16);
    }
    psh[i] = vs; psc[i] = vc;
  }
  __syncthreads();   // all halo reads complete before any f32 overwrite

  const float bs = bshift[n];
  const float bc = bscale[n];

  for (int c = 0; c < 4; ++c) {             // 4 chunks of 16 t-rows
    const int T = t0 + c * 16;
    unsigned int cu[16];
#pragma unroll
    for (int u = 0; u < 16; ++u) cu[u] = pk[base + (size_t)(T + u) * 1024];
    unsigned short yv[16];
#pragma unroll
    for (int u = 0; u < 16; ++u) yv[u] = ya[base + (size_t)(T + u) * 1024];
    float csh[16], csc[16];
#pragma unroll
    for (int u = 0; u < 16; ++u) {
      csh[u] = bf2f(cu[u] & 0xffffu);
      csc[u] = bf2f(cu[u] >> 16);
    }
#pragma unroll
    for (int u = 0; u < 16; ++u) {
      float fs = 0.f, fc = 0.f;
#pragma unroll
      for (int k = 0; k < 16; ++k) {
        const int d = u - k;
        const float vs = (d >= 0) ? csh[d] : psh[15 + d];
        const float vc = (d >= 0) ? csc[d] : psc[15 + d];
        fs = fmaf(g[k], vs, fs);
        fc = fmaf(g[k], vc, fc);
      }
      const int t = T + u;
      float inv = invf;
      if (t < 15) {                          // batch start: partial norm
        float s = 0.f;
#pragma unroll
        for (int k = 0; k < 16; ++k) s += (k <= t) ? g[k] : 0.f;
        inv = 1.0f / s;
      }
      const float shiftv = fs * inv + bs;
      const float scalev = fc * inv + bc;
      const float aff = bf2f((unsigned int)yv[u]);
      outf[base + (size_t)t * 1024] = scalev * aff + shiftv;
    }
#pragma unroll
    for (int i = 0; i < 15; ++i) { psh[i] = csh[i + 1]; psc[i] = csc[i + 1]; }
  }
}

// ---------------------------------------------------------------------------
// Workspace layout (22 MiB, proven safe; ws_size known to be in [22,38) MiB):
//   ya  : ws + 0        16 MiB (affine, bf16)
//   Wta : ws + 16 MiB    2 MiB (Wa^T bf16)
//   Wts : ws + 18 MiB    2 MiB (Wshift^T bf16)
//   Wtc : ws + 20 MiB    2 MiB (Wscale^T bf16)
// d_out doubles as the (ysh,ysc) bf16-pair slab before filter_combine
// overwrites it in place with the final f32 output.
// ---------------------------------------------------------------------------
extern "C" void kernel_launch(void* const* d_in, const int* in_sizes, int n_in,
                              void* d_out, int out_size, void* d_ws, size_t ws_size,
                              hipStream_t stream) {
  const float* x   = (const float*)d_in[0];
  const float* Wa  = (const float*)d_in[1];
  const float* ba  = (const float*)d_in[2];
  const float* Wsh = (const float*)d_in[3];
  const float* bsh = (const float*)d_in[4];
  const float* Wsc = (const float*)d_in[5];
  const float* bsc = (const float*)d_in[6];

  char* ws = (char*)d_ws;
  unsigned short* ya  = (unsigned short*)(ws);
  unsigned short* Wta = (unsigned short*)(ws + (16u << 20));
  unsigned short* Wts = (unsigned short*)(ws + (18u << 20));
  unsigned short* Wtc = (unsigned short*)(ws + (20u << 20));

  hipLaunchKernelGGL(wconv, dim3(16, 16, 3), dim3(256), 0, stream,
                     Wa, Wsh, Wsc, Wta, Wts, Wtc);
  hipLaunchKernelGGL(fused_gemm, dim3(256), dim3(512), 0, stream,
                     x, Wta, Wts, Wtc, ba, ya, (unsigned int*)d_out);
  hipLaunchKernelGGL(filter_combine, dim3(256), dim3(512), 0, stream,
                     d_out, ya, bsh, bsc);
}